// Round 5
// baseline (255.270 us; speedup 1.0000x reference)
//
#include <hip/hip_runtime.h>
#include <hip/hip_bf16.h>

#define U_DIM 1024
#define H_DIM 4096
#define N_DIM 8192   // 2H
#define K_DIM 4096   // = H

#define BM 64
#define BN 128
#define BK 32
#define NT (K_DIM / BK)   // 128 K-steps

typedef __attribute__((ext_vector_type(8))) short bf16x8;
typedef __attribute__((ext_vector_type(4))) float f32x4;

__device__ inline unsigned short f2bf(float f) {
  union { float f; unsigned u; } a; a.f = f;
  unsigned r = a.u + 0x7fffu + ((a.u >> 16) & 1u);  // RNE
  return (unsigned short)(r >> 16);
}

__device__ inline void gload_lds16(const void* g, void* l) {
  __builtin_amdgcn_global_load_lds(
      (const __attribute__((address_space(1))) unsigned*)(g),
      (__attribute__((address_space(3))) unsigned*)(l), 16, 0, 0);
}

// ---------------- x fp32 -> bf16 ----------------
__global__ __launch_bounds__(256) void convert_x_kernel(
    const float* __restrict__ x, unsigned short* __restrict__ xb) {
  size_t i = (size_t)blockIdx.x * 256 + threadIdx.x;   // each handles 4 elems
  float4 v = ((const float4*)x)[i];
  ushort4 o;
  o.x = f2bf(v.x); o.y = f2bf(v.y); o.z = f2bf(v.z); o.w = f2bf(v.w);
  ((ushort4*)xb)[i] = o;
}

// ---------------- ssm_proj [K][N] fp32 -> Bt [N][K] bf16 ----------------
// 64x64 tile; fp32 float4 loads -> LDS (padded 65) -> bf16x8 (16B) stores.
// Load phase 2-way banks (free); store col-reads 2-way (stride 65) (free).
__global__ __launch_bounds__(256) void transpose_b_kernel(
    const float* __restrict__ B, unsigned short* __restrict__ Bt) {
  __shared__ float tile[64][65];
  const int kt = blockIdx.x & 63;    // K/64 = 64 k-tiles
  const int nt = blockIdx.x >> 6;    // N/64 = 128 n-tiles
  const int k0 = kt * 64, n0 = nt * 64;
  const int tid = threadIdx.x;
  const int lr = tid >> 4;          // 0..15
  const int lc = (tid & 15) * 4;    // 0..60

#pragma unroll
  for (int it = 0; it < 4; ++it) {
    int r = it * 16 + lr;           // local k row
    float4 v = *(const float4*)(&B[(size_t)(k0 + r) * N_DIM + n0 + lc]);
    tile[r][lc + 0] = v.x; tile[r][lc + 1] = v.y;
    tile[r][lc + 2] = v.z; tile[r][lc + 3] = v.w;
  }
  __syncthreads();
  const int sc = tid & 7;           // k-chunk (8 k each)
  const int sr = tid >> 3;          // 0..31 n-row
#pragma unroll
  for (int it = 0; it < 2; ++it) {
    int rn = it * 32 + sr;
    union { bf16x8 v; unsigned short u[8]; } o;
#pragma unroll
    for (int j = 0; j < 8; ++j) o.u[j] = f2bf(tile[sc * 8 + j][rn]);
    *(bf16x8*)(&Bt[(size_t)(n0 + rn) * K_DIM + k0 + sc * 8]) = o.v;
  }
}

// ------- bf16 MFMA GEMM: BM=64 -> grid 1024 (4 blocks/CU), dbuf, gload_lds -------
// Reverts round-4's B-direct staging (regressed). Both A and B staged bf16 via
// global_load_lds w/ pre-swizzled source (slot ^ ((row>>1)&3)); reads apply the
// same XOR -> <=2 lanes/bank (free). 4 independent blocks/CU stagger the
// end-of-iter vmcnt drains (m97/m102 grid-1024 mechanism).
template <bool FUSE>
__global__ __launch_bounds__(256, 4) void gemm_conv_kernel(
    const unsigned short* __restrict__ Abf,   // [U][K] bf16
    const unsigned short* __restrict__ Btbf,  // [N][K] bf16
    const float* __restrict__ conv_states,    // [4][U][N]
    const float* __restrict__ conv_wts,       // [4][N]
    const float* __restrict__ conv_bias,      // [N]
    float* __restrict__ out,                  // [U][N]
    float* __restrict__ ns)                   // [4][U][N] new_states base
{
  // 2 buffers x (A 4KB + B 8KB) = 24KB
  __shared__ char smem[2 * 12288];

  const int orig = blockIdx.x;
  const int bid  = (orig & 7) * 128 + (orig >> 3);  // XCD chunk swizzle (1024%8==0)
  const int brow = bid & 15;             // 16 row-blocks
  const int bcol = bid >> 4;             // 64 col-blocks
  const int tid  = threadIdx.x;
  const int lane = tid & 63;
  const int wid  = tid >> 6;             // 0..3; wave covers 64 rows x 32 cols

  f32x4 acc[4][2];
#pragma unroll
  for (int m = 0; m < 4; ++m)
#pragma unroll
    for (int n = 0; n < 2; ++n)
#pragma unroll
      for (int r = 0; r < 4; ++r) acc[m][n][r] = 0.0f;

  // staging: thread t covers LDS byte t*16 of each 4KB chunk
  const int srow   = tid >> 2;                     // tile row 0..63
  const int swslot = (tid & 3) ^ ((tid >> 3) & 3); // pre-swizzled global slot
  const int l15 = lane & 15;
  const int fs  = lane >> 4;                       // wanted k-slot
  const int rds = (fs ^ ((l15 >> 1) & 3)) * 16;    // swizzled read byte offset

  const unsigned short* gA  = Abf  + (size_t)(brow * BM + srow) * K_DIM + swslot * 8;
  const unsigned short* gB0 = Btbf + (size_t)(bcol * BN + srow) * K_DIM + swslot * 8;
  const unsigned short* gB1 = gB0 + (size_t)64 * K_DIM;

  // prologue: stage tile 0 into buf 0
  gload_lds16(gA,  smem + wid * 1024);
  gload_lds16(gB0, smem + 4096 + wid * 1024);
  gload_lds16(gB1, smem + 8192 + wid * 1024);
  __syncthreads();

  int p = 0;
  for (int t = 0; t < NT; ++t) {
    const int q = p ^ 1;
    // issue next tile's loads FIRST (in flight across the MFMA phase)
    if (t + 1 < NT) {
      const int koff = (t + 1) * BK;
      char* base = smem + q * 12288;
      gload_lds16(gA  + koff, base + wid * 1024);
      gload_lds16(gB0 + koff, base + 4096 + wid * 1024);
      gload_lds16(gB1 + koff, base + 8192 + wid * 1024);
    }

    const char* sA = smem + p * 12288;
    const char* sB = sA + 4096;
    bf16x8 af[4], bv[2];
#pragma unroll
    for (int m = 0; m < 4; ++m)
      af[m] = *(const bf16x8*)(sA + (m * 16 + l15) * 64 + rds);
#pragma unroll
    for (int n = 0; n < 2; ++n)
      bv[n] = *(const bf16x8*)(sB + (wid * 32 + n * 16 + l15) * 64 + rds);

#pragma unroll
    for (int m = 0; m < 4; ++m)
#pragma unroll
      for (int n = 0; n < 2; ++n)
        acc[m][n] = __builtin_amdgcn_mfma_f32_16x16x32_bf16(af[m], bv[n], acc[m][n], 0, 0, 0);

    __syncthreads();   // drain for buf q lands after the compute phase
    p ^= 1;
  }

  // epilogue: out = w0*cs1 + w1*cs2 + w2*cs3 + w3*xp + bias ; ns3 = xp
  // FUSE: also new_states[0..2] = conv_states[1..3] (replaces the d2d memcpy)
  const size_t PL = (size_t)U_DIM * N_DIM;
  const float* cs1 = conv_states + PL;
  const float* cs2 = conv_states + 2 * PL;
  const float* cs3 = conv_states + 3 * PL;
  float* ns0 = ns;
  float* ns1 = ns + PL;
  float* ns2 = ns + 2 * PL;
  float* ns3 = ns + 3 * PL;

#pragma unroll
  for (int n = 0; n < 2; ++n) {
    const int d = bcol * BN + wid * 32 + n * 16 + l15;
    const float w0 = conv_wts[d];
    const float w1 = conv_wts[N_DIM + d];
    const float w2 = conv_wts[2 * N_DIM + d];
    const float w3 = conv_wts[3 * N_DIM + d];
    const float bs = conv_bias[d];
#pragma unroll
    for (int m = 0; m < 4; ++m) {
#pragma unroll
      for (int r = 0; r < 4; ++r) {
        const int u = brow * BM + m * 16 + fs * 4 + r;
        const size_t idx = (size_t)u * N_DIM + d;
        const float xpv = acc[m][n][r];
        const float c1 = cs1[idx], c2 = cs2[idx], c3 = cs3[idx];
        out[idx] = w0 * c1 + w1 * c2 + w2 * c3 + w3 * xpv + bs;
        if (FUSE) { ns0[idx] = c1; ns1[idx] = c2; ns2[idx] = c3; }
        ns3[idx] = xpv;
      }
    }
  }
}

extern "C" void kernel_launch(void* const* d_in, const int* in_sizes, int n_in,
                              void* d_out, int out_size, void* d_ws, size_t ws_size,
                              hipStream_t stream) {
  (void)in_sizes; (void)n_in; (void)out_size;
  const float* x           = (const float*)d_in[0];
  const float* ssm_proj    = (const float*)d_in[1];
  const float* conv_states = (const float*)d_in[2];
  const float* conv_wts    = (const float*)d_in[3];
  const float* conv_bias   = (const float*)d_in[4];
  float* outp = (float*)d_out;

  const size_t OUT_ELEMS = (size_t)U_DIM * N_DIM;        // 8M floats
  float* ns = outp + OUT_ELEMS;                          // new_states base

  const size_t BT_BYTES = (size_t)N_DIM * K_DIM * sizeof(unsigned short);  // 64MB
  const size_t XB_BYTES = (size_t)U_DIM * K_DIM * sizeof(unsigned short);  // 8MB
  const int GRID = (U_DIM / BM) * (N_DIM / BN);          // 1024

  if (ws_size >= BT_BYTES + XB_BYTES) {
    // scratch in d_ws -> GEMM epilogue writes new_states[0..2] directly
    unsigned short* Btbf = (unsigned short*)d_ws;
    unsigned short* xbf  = (unsigned short*)((char*)d_ws + BT_BYTES);
    convert_x_kernel<<<(U_DIM * H_DIM / 4) / 256, 256, 0, stream>>>(x, xbf);
    transpose_b_kernel<<<(N_DIM / 64) * (K_DIM / 64), 256, 0, stream>>>(ssm_proj, Btbf);
    gemm_conv_kernel<true><<<GRID, 256, 0, stream>>>(
        xbf, Btbf, conv_states, conv_wts, conv_bias, outp, ns);
  } else {
    // fallback: scratch inside d_out's new_states[0:2] region, copy after GEMM
    unsigned short* Btbf = (unsigned short*)ns;
    unsigned short* xbf  = (unsigned short*)(ns + 2 * OUT_ELEMS);
    convert_x_kernel<<<(U_DIM * H_DIM / 4) / 256, 256, 0, stream>>>(x, xbf);
    transpose_b_kernel<<<(N_DIM / 64) * (K_DIM / 64), 256, 0, stream>>>(ssm_proj, Btbf);
    gemm_conv_kernel<false><<<GRID, 256, 0, stream>>>(
        xbf, Btbf, conv_states, conv_wts, conv_bias, outp, ns);
    hipMemcpyAsync(ns, conv_states + OUT_ELEMS, 3 * OUT_ELEMS * sizeof(float),
                   hipMemcpyDeviceToDevice, stream);
  }
}

// Round 6
// 245.117 us; speedup vs baseline: 1.0414x; 1.0414x over previous
//
#include <hip/hip_runtime.h>
#include <hip/hip_bf16.h>

#define U_DIM 1024
#define H_DIM 4096
#define N_DIM 8192   // 2H
#define K_DIM 4096   // = H

#define BM 128
#define BN 128
#define BK 32
#define NT (K_DIM / BK)   // 128 K-steps
#define BUFB 16384        // bytes per ring buffer (A 8KB + B 8KB)

typedef __attribute__((ext_vector_type(8))) short bf16x8;
typedef __attribute__((ext_vector_type(4))) float f32x4;

__device__ inline unsigned short f2bf(float f) {
  union { float f; unsigned u; } a; a.f = f;
  unsigned r = a.u + 0x7fffu + ((a.u >> 16) & 1u);  // RNE
  return (unsigned short)(r >> 16);
}

__device__ inline void gload_lds16(const void* g, void* l) {
  __builtin_amdgcn_global_load_lds(
      (const __attribute__((address_space(1))) unsigned*)(g),
      (__attribute__((address_space(3))) unsigned*)(l), 16, 0, 0);
}

// ---------------- x fp32 -> bf16 ----------------
__global__ __launch_bounds__(256) void convert_x_kernel(
    const float* __restrict__ x, unsigned short* __restrict__ xb) {
  size_t i = (size_t)blockIdx.x * 256 + threadIdx.x;   // each handles 4 elems
  float4 v = ((const float4*)x)[i];
  ushort4 o;
  o.x = f2bf(v.x); o.y = f2bf(v.y); o.z = f2bf(v.z); o.w = f2bf(v.w);
  ((ushort4*)xb)[i] = o;
}

// ---------------- ssm_proj [K][N] fp32 -> Bt [N][K] bf16 ----------------
__global__ __launch_bounds__(256) void transpose_b_kernel(
    const float* __restrict__ B, unsigned short* __restrict__ Bt) {
  __shared__ float tile[64][65];
  const int kt = blockIdx.x & 63;    // K/64 = 64 k-tiles
  const int nt = blockIdx.x >> 6;    // N/64 = 128 n-tiles
  const int k0 = kt * 64, n0 = nt * 64;
  const int tid = threadIdx.x;
  const int lr = tid >> 4;          // 0..15
  const int lc = (tid & 15) * 4;    // 0..60

#pragma unroll
  for (int it = 0; it < 4; ++it) {
    int r = it * 16 + lr;           // local k row
    float4 v = *(const float4*)(&B[(size_t)(k0 + r) * N_DIM + n0 + lc]);
    tile[r][lc + 0] = v.x; tile[r][lc + 1] = v.y;
    tile[r][lc + 2] = v.z; tile[r][lc + 3] = v.w;
  }
  __syncthreads();
  const int sc = tid & 7;           // k-chunk (8 k each)
  const int sr = tid >> 3;          // 0..31 n-row
#pragma unroll
  for (int it = 0; it < 2; ++it) {
    int rn = it * 32 + sr;
    union { bf16x8 v; unsigned short u[8]; } o;
#pragma unroll
    for (int j = 0; j < 8; ++j) o.u[j] = f2bf(tile[sc * 8 + j][rn]);
    *(bf16x8*)(&Bt[(size_t)(n0 + rn) * K_DIM + k0 + sc * 8]) = o.v;
  }
}

// ------- bf16 MFMA GEMM: r3 data path + T4 counted-vmcnt 4-deep ring pipeline -------
// Per iter t: wait vmcnt(4) (tile t's 2 DMAs done; t+1,t+2 stay in flight) +
// lgkmcnt(0) (my reads of t-1 done) -> raw s_barrier -> issue tile t+3's DMA
// into the ring slot reads of t-1 just vacated -> ds_read+MFMA tile t.
// Main-loop waits NEVER drain to 0 (T4, m218). Swizzle as r2/r3 (0 conflicts).
template <bool FUSE>
__global__ __launch_bounds__(512, 4) void gemm_conv_kernel(
    const unsigned short* __restrict__ Abf,   // [U][K] bf16
    const unsigned short* __restrict__ Btbf,  // [N][K] bf16
    const float* __restrict__ conv_states,    // [4][U][N]
    const float* __restrict__ conv_wts,       // [4][N]
    const float* __restrict__ conv_bias,      // [N]
    float* __restrict__ out,                  // [U][N]
    float* __restrict__ ns)                   // [4][U][N] new_states base
{
  __shared__ char smem[4 * BUFB];   // 64KB ring: 4 x (A 8KB + B 8KB)

  const int bid0 = blockIdx.x;
  const int bid  = (bid0 & 7) * 64 + (bid0 >> 3);  // bijective XCD swizzle (512%8==0)
  const int brow = bid & 7;              // 8 row-blocks
  const int bcol = bid >> 3;             // 64 col-blocks
  const int tid  = threadIdx.x;
  const int lane = tid & 63;
  const int wid  = tid >> 6;             // 0..7
  const int wr = wid >> 2;               // 0..1 -> 64-row group
  const int wc = wid & 3;                // 0..3 -> 32-col group

  f32x4 acc[4][2];
#pragma unroll
  for (int m = 0; m < 4; ++m)
#pragma unroll
    for (int n = 0; n < 2; ++n)
#pragma unroll
      for (int r = 0; r < 4; ++r) acc[m][n][r] = 0.0f;

  // staging: 512 lanes x 16B = 8KB = one full [128][BK] bf16 tile per matrix
  const int srow   = wid * 16 + (lane >> 2);         // 0..127 tile row
  const int sslot  = lane & 3;                       // 16B slot in 64B row
  const int swslot = sslot ^ ((srow >> 1) & 3);      // pre-swizzled global slot
  const int fs     = lane >> 4;                      // wanted k-slot
  const int rdslot = fs ^ ((lane >> 1) & 3);         // swizzled read slot
  const int fra    = wr * 64 + (lane & 15);          // A fragment row base
  const int frb    = wc * 32 + (lane & 15);          // B fragment row base

  const unsigned short* gA0 = Abf  + (size_t)(brow * BM + srow) * K_DIM + swslot * 8;
  const unsigned short* gB0 = Btbf + (size_t)(bcol * BN + srow) * K_DIM + swslot * 8;

  // prologue: issue tiles 0,1,2 into ring slots 0,1,2 (6 DMAs in flight)
#pragma unroll
  for (int t = 0; t < 3; ++t) {
    char* base = smem + t * BUFB;
    gload_lds16(gA0 + (size_t)t * BK, base + wid * 1024);
    gload_lds16(gB0 + (size_t)t * BK, base + 8192 + wid * 1024);
  }

  int cb = 0;   // ring slot holding tile t
#pragma unroll 1
  for (int t = 0; t < NT; ++t) {
    // tile t's DMAs done; deeper tiles stay in flight (counted, not drained)
    if (t + 2 < NT)      asm volatile("s_waitcnt vmcnt(4) lgkmcnt(0)" ::: "memory");
    else if (t + 1 < NT) asm volatile("s_waitcnt vmcnt(2) lgkmcnt(0)" ::: "memory");
    else                 asm volatile("s_waitcnt vmcnt(0) lgkmcnt(0)" ::: "memory");
    __builtin_amdgcn_s_barrier();          // publish tile t; retire reads of t-1
    __builtin_amdgcn_sched_barrier(0);     // nothing crosses (rule #18)

    if (t + 3 < NT) {                      // refill the slot reads of t-1 vacated
      const int ib = (cb >= 1) ? cb - 1 : 3;   // (cb+3)%4
      char* base = smem + ib * BUFB;
      const size_t koff = (size_t)(t + 3) * BK;
      gload_lds16(gA0 + koff, base + wid * 1024);
      gload_lds16(gB0 + koff, base + 8192 + wid * 1024);
    }

    const char* sA = smem + cb * BUFB;
    const char* sB = sA + 8192;
    bf16x8 af[4], bv[2];
#pragma unroll
    for (int m = 0; m < 4; ++m)
      af[m] = *(const bf16x8*)(sA + (fra + m * 16) * (BK * 2) + rdslot * 16);
#pragma unroll
    for (int n = 0; n < 2; ++n)
      bv[n] = *(const bf16x8*)(sB + (frb + n * 16) * (BK * 2) + rdslot * 16);

#pragma unroll
    for (int m = 0; m < 4; ++m)
#pragma unroll
      for (int n = 0; n < 2; ++n)
        acc[m][n] = __builtin_amdgcn_mfma_f32_16x16x32_bf16(af[m], bv[n], acc[m][n], 0, 0, 0);

    cb = (cb == 3) ? 0 : cb + 1;
  }

  // epilogue: out = w0*cs1 + w1*cs2 + w2*cs3 + w3*xp + bias ; ns3 = xp
  // FUSE: also new_states[0..2] = conv_states[1..3] (replaces the d2d memcpy)
  const size_t PL = (size_t)U_DIM * N_DIM;
  const float* cs1 = conv_states + PL;
  const float* cs2 = conv_states + 2 * PL;
  const float* cs3 = conv_states + 3 * PL;
  float* ns0 = ns;
  float* ns1 = ns + PL;
  float* ns2 = ns + 2 * PL;
  float* ns3 = ns + 3 * PL;

#pragma unroll
  for (int n = 0; n < 2; ++n) {
    const int d = bcol * BN + wc * 32 + n * 16 + (lane & 15);
    const float w0 = conv_wts[d];
    const float w1 = conv_wts[N_DIM + d];
    const float w2 = conv_wts[2 * N_DIM + d];
    const float w3 = conv_wts[3 * N_DIM + d];
    const float bs = conv_bias[d];
#pragma unroll
    for (int m = 0; m < 4; ++m) {
#pragma unroll
      for (int r = 0; r < 4; ++r) {
        const int u = brow * BM + wr * 64 + m * 16 + fs * 4 + r;
        const size_t idx = (size_t)u * N_DIM + d;
        const float xpv = acc[m][n][r];
        const float c1 = cs1[idx], c2 = cs2[idx], c3 = cs3[idx];
        out[idx] = w0 * c1 + w1 * c2 + w2 * c3 + w3 * xpv + bs;
        if (FUSE) { ns0[idx] = c1; ns1[idx] = c2; ns2[idx] = c3; }
        ns3[idx] = xpv;
      }
    }
  }
}

extern "C" void kernel_launch(void* const* d_in, const int* in_sizes, int n_in,
                              void* d_out, int out_size, void* d_ws, size_t ws_size,
                              hipStream_t stream) {
  (void)in_sizes; (void)n_in; (void)out_size;
  const float* x           = (const float*)d_in[0];
  const float* ssm_proj    = (const float*)d_in[1];
  const float* conv_states = (const float*)d_in[2];
  const float* conv_wts    = (const float*)d_in[3];
  const float* conv_bias   = (const float*)d_in[4];
  float* outp = (float*)d_out;

  const size_t OUT_ELEMS = (size_t)U_DIM * N_DIM;        // 8M floats
  float* ns = outp + OUT_ELEMS;                          // new_states base

  const size_t BT_BYTES = (size_t)N_DIM * K_DIM * sizeof(unsigned short);  // 64MB
  const size_t XB_BYTES = (size_t)U_DIM * K_DIM * sizeof(unsigned short);  // 8MB
  const int GRID = (U_DIM / BM) * (N_DIM / BN);          // 512

  if (ws_size >= BT_BYTES + XB_BYTES) {
    // scratch in d_ws -> GEMM epilogue writes new_states[0..2] directly
    unsigned short* Btbf = (unsigned short*)d_ws;
    unsigned short* xbf  = (unsigned short*)((char*)d_ws + BT_BYTES);
    convert_x_kernel<<<(U_DIM * H_DIM / 4) / 256, 256, 0, stream>>>(x, xbf);
    transpose_b_kernel<<<(N_DIM / 64) * (K_DIM / 64), 256, 0, stream>>>(ssm_proj, Btbf);
    gemm_conv_kernel<true><<<GRID, 512, 0, stream>>>(
        xbf, Btbf, conv_states, conv_wts, conv_bias, outp, ns);
  } else {
    // fallback: scratch inside d_out's new_states[0:2] region, copy after GEMM
    unsigned short* Btbf = (unsigned short*)ns;
    unsigned short* xbf  = (unsigned short*)(ns + 2 * OUT_ELEMS);
    convert_x_kernel<<<(U_DIM * H_DIM / 4) / 256, 256, 0, stream>>>(x, xbf);
    transpose_b_kernel<<<(N_DIM / 64) * (K_DIM / 64), 256, 0, stream>>>(ssm_proj, Btbf);
    gemm_conv_kernel<false><<<GRID, 512, 0, stream>>>(
        xbf, Btbf, conv_states, conv_wts, conv_bias, outp, ns);
    hipMemcpyAsync(ns, conv_states + OUT_ELEMS, 3 * OUT_ELEMS * sizeof(float),
                   hipMemcpyDeviceToDevice, stream);
  }
}

// Round 7
// 206.700 us; speedup vs baseline: 1.2350x; 1.1859x over previous
//
#include <hip/hip_runtime.h>
#include <hip/hip_bf16.h>

#define U_DIM 1024
#define H_DIM 4096
#define N_DIM 8192   // 2H
#define K_DIM 4096   // = H

#define BM 128
#define BN 256
#define BK 64
#define NT (K_DIM / BK)            // 64 K-tiles
#define SLOTB (BM*BK*2 + BN*BK*2)  // 16KB A + 32KB B = 49152 B per ring slot

typedef __attribute__((ext_vector_type(8))) short bf16x8;
typedef __attribute__((ext_vector_type(4))) float f32x4;

__device__ inline unsigned short f2bf(float f) {
  union { float f; unsigned u; } a; a.f = f;
  unsigned r = a.u + 0x7fffu + ((a.u >> 16) & 1u);  // RNE
  return (unsigned short)(r >> 16);
}

__device__ inline void gload_lds16(const void* g, void* l) {
  __builtin_amdgcn_global_load_lds(
      (const __attribute__((address_space(1))) unsigned*)(g),
      (__attribute__((address_space(3))) unsigned*)(l), 16, 0, 0);
}

// ---------------- x fp32 -> bf16 ----------------
__global__ __launch_bounds__(256) void convert_x_kernel(
    const float* __restrict__ x, unsigned short* __restrict__ xb) {
  size_t i = (size_t)blockIdx.x * 256 + threadIdx.x;   // each handles 4 elems
  float4 v = ((const float4*)x)[i];
  ushort4 o;
  o.x = f2bf(v.x); o.y = f2bf(v.y); o.z = f2bf(v.z); o.w = f2bf(v.w);
  ((ushort4*)xb)[i] = o;
}

// ---------------- ssm_proj [K][N] fp32 -> Bt [N][K] bf16 ----------------
__global__ __launch_bounds__(256) void transpose_b_kernel(
    const float* __restrict__ B, unsigned short* __restrict__ Bt) {
  __shared__ float tile[64][65];
  const int kt = blockIdx.x & 63;    // K/64 = 64 k-tiles
  const int nt = blockIdx.x >> 6;    // N/64 = 128 n-tiles
  const int k0 = kt * 64, n0 = nt * 64;
  const int tid = threadIdx.x;
  const int lr = tid >> 4;          // 0..15
  const int lc = (tid & 15) * 4;    // 0..60

#pragma unroll
  for (int it = 0; it < 4; ++it) {
    int r = it * 16 + lr;           // local k row
    float4 v = *(const float4*)(&B[(size_t)(k0 + r) * N_DIM + n0 + lc]);
    tile[r][lc + 0] = v.x; tile[r][lc + 1] = v.y;
    tile[r][lc + 2] = v.z; tile[r][lc + 3] = v.w;
  }
  __syncthreads();
  const int sc = tid & 7;           // k-chunk (8 k each)
  const int sr = tid >> 3;          // 0..31 n-row
#pragma unroll
  for (int it = 0; it < 2; ++it) {
    int rn = it * 32 + sr;
    union { bf16x8 v; unsigned short u[8]; } o;
#pragma unroll
    for (int j = 0; j < 8; ++j) o.u[j] = f2bf(tile[sc * 8 + j][rn]);
    *(bf16x8*)(&Bt[(size_t)(n0 + rn) * K_DIM + k0 + sc * 8]) = o.v;
  }
}

// ------- bf16 MFMA GEMM: 128x256 tile, BK=64, 3-slot LDS ring, counted vmcnt -------
// Deep pipeline (m201 mechanism): per K-tile t, issue tile t+2's 6 DMAs into
// ring slot (t+2)%3 (whose reads retired at barrier t-1), compute 2x16-MFMA
// clusters (k-halves) under setprio, then ONE vmcnt(6)+lgkmcnt(0)+s_barrier:
// t+1's loads are complete, t+2's stay IN FLIGHT across the barrier (T4).
// LDS rows 128B, slot^(row&7) swizzle both sides -> 2 lanes/bank (free).
template <bool FUSE>
__global__ __launch_bounds__(512, 1) void gemm_conv_kernel(
    const unsigned short* __restrict__ Abf,   // [U][K] bf16
    const unsigned short* __restrict__ Btbf,  // [N][K] bf16
    const float* __restrict__ conv_states,    // [4][U][N]
    const float* __restrict__ conv_wts,       // [4][N]
    const float* __restrict__ conv_bias,      // [N]
    float* __restrict__ out,                  // [U][N]
    float* __restrict__ ns)                   // [4][U][N] new_states base
{
  __shared__ char smem[3 * SLOTB];   // 144KB -> 1 block/CU

  const int orig = blockIdx.x;                    // grid 256 = 8 XCD x 32
  const int bid  = (orig & 7) * 32 + (orig >> 3); // XCD-chunked swizzle
  const int brow = bid & 7;                       // 8 row-blocks  (BM=128)
  const int bcol = bid >> 3;                      // 32 col-blocks (BN=256)
  const int tid  = threadIdx.x;
  const int lane = tid & 63;
  const int wid  = tid >> 6;             // 0..7
  const int wr = wid >> 2;               // 0..1 -> 64-row group
  const int wc = wid & 3;                // 0..3 -> 64-col group

  f32x4 acc[4][4];
#pragma unroll
  for (int m = 0; m < 4; ++m)
#pragma unroll
    for (int n = 0; n < 4; ++n)
#pragma unroll
      for (int r = 0; r < 4; ++r) acc[m][n][r] = 0.0f;

  // ---- staging (6 x gload_lds / thread / K-tile; dest = uniform base + tid*16)
  const int rowa = tid >> 3;                       // 0..63
  const int gsl  = (tid & 7) ^ (rowa & 7);         // pre-swizzled global 16B slot
  const int tid16 = tid * 16;
  const unsigned short* gA0 = Abf  + (size_t)(brow * BM + rowa) * K_DIM + gsl * 8;
  const unsigned short* gA1 = gA0 + (size_t)64 * K_DIM;
  const unsigned short* gB0 = Btbf + (size_t)(bcol * BN + rowa) * K_DIM + gsl * 8;
  const unsigned short* gB1 = gB0 + (size_t)64  * K_DIM;
  const unsigned short* gB2 = gB0 + (size_t)128 * K_DIM;
  const unsigned short* gB3 = gB0 + (size_t)192 * K_DIM;

#define STAGE(kt, base) do {                               \
    const size_t ko = (size_t)(kt) * BK;                   \
    gload_lds16(gA0 + ko, (base) + tid16);                 \
    gload_lds16(gA1 + ko, (base) + 8192  + tid16);         \
    gload_lds16(gB0 + ko, (base) + 16384 + tid16);         \
    gload_lds16(gB1 + ko, (base) + 24576 + tid16);         \
    gload_lds16(gB2 + ko, (base) + 32768 + tid16);         \
    gload_lds16(gB3 + ko, (base) + 40960 + tid16);         \
  } while (0)

  // ---- fragment read offsets (LDS rows 128B; slot^(row&7), row&7 == l15&7)
  const int l15 = lane & 15;
  const int fs  = lane >> 4;             // 16B k-slot within 64B half
  const int rsw = l15 & 7;
  int aoff[4], boff[4];
#pragma unroll
  for (int m = 0; m < 4; ++m) aoff[m] = (wr * 64 + m * 16 + l15) * 128;
#pragma unroll
  for (int n = 0; n < 4; ++n) boff[n] = (wc * 64 + n * 16 + l15) * 128;

  // ---- prologue: stage tiles 0,1 into slots 0,1; publish tile 0
  STAGE(0, smem);
  STAGE(1, smem + SLOTB);
  asm volatile("s_waitcnt vmcnt(6)" ::: "memory");   // tile 0 done; tile 1 in flight
  __builtin_amdgcn_s_barrier();
  __builtin_amdgcn_sched_barrier(0);

  int s0 = 0, s2 = 2;   // slot of tile t, slot of tile t+2
#pragma unroll 1
  for (int t = 0; t < NT; ++t) {
    if (t + 2 < NT) STAGE(t + 2, smem + s2 * SLOTB);

    const char* curA = smem + s0 * SLOTB;
    const char* curB = curA + 16384;
#pragma unroll
    for (int kh = 0; kh < 2; ++kh) {
      const int ksl = ((kh * 4 + fs) ^ rsw) * 16;
      bf16x8 af[4], bv[4];
#pragma unroll
      for (int m = 0; m < 4; ++m) af[m] = *(const bf16x8*)(curA + aoff[m] + ksl);
#pragma unroll
      for (int n = 0; n < 4; ++n) bv[n] = *(const bf16x8*)(curB + boff[n] + ksl);
      __builtin_amdgcn_s_setprio(1);
#pragma unroll
      for (int m = 0; m < 4; ++m)
#pragma unroll
        for (int n = 0; n < 4; ++n)
          acc[m][n] = __builtin_amdgcn_mfma_f32_16x16x32_bf16(af[m], bv[n], acc[m][n], 0, 0, 0);
      __builtin_amdgcn_s_setprio(0);
    }

    if (t + 1 < NT) {
      if (t + 2 < NT) asm volatile("s_waitcnt vmcnt(6) lgkmcnt(0)" ::: "memory");
      else            asm volatile("s_waitcnt vmcnt(0) lgkmcnt(0)" ::: "memory");
      __builtin_amdgcn_s_barrier();          // publish tile t+1; retire reads of t
      __builtin_amdgcn_sched_barrier(0);     // rule #18: nothing crosses
    }
    s0 = (s0 == 2) ? 0 : s0 + 1;
    s2 = (s2 == 2) ? 0 : s2 + 1;
  }
#undef STAGE

  // epilogue: out = w0*cs1 + w1*cs2 + w2*cs3 + w3*xp + bias ; ns3 = xp
  // FUSE: also new_states[0..2] = conv_states[1..3] (replaces the d2d memcpy)
  const size_t PL = (size_t)U_DIM * N_DIM;
  const float* cs1 = conv_states + PL;
  const float* cs2 = conv_states + 2 * PL;
  const float* cs3 = conv_states + 3 * PL;
  float* ns0 = ns;
  float* ns1 = ns + PL;
  float* ns2 = ns + 2 * PL;
  float* ns3 = ns + 3 * PL;

#pragma unroll
  for (int n = 0; n < 4; ++n) {
    const int d = bcol * BN + wc * 64 + n * 16 + l15;
    const float w0 = conv_wts[d];
    const float w1 = conv_wts[N_DIM + d];
    const float w2 = conv_wts[2 * N_DIM + d];
    const float w3 = conv_wts[3 * N_DIM + d];
    const float bs = conv_bias[d];
#pragma unroll
    for (int m = 0; m < 4; ++m) {
#pragma unroll
      for (int r = 0; r < 4; ++r) {
        const int u = brow * BM + wr * 64 + m * 16 + fs * 4 + r;
        const size_t idx = (size_t)u * N_DIM + d;
        const float xpv = acc[m][n][r];
        const float c1 = cs1[idx], c2 = cs2[idx], c3 = cs3[idx];
        out[idx] = w0 * c1 + w1 * c2 + w2 * c3 + w3 * xpv + bs;
        if (FUSE) { ns0[idx] = c1; ns1[idx] = c2; ns2[idx] = c3; }
        ns3[idx] = xpv;
      }
    }
  }
}

extern "C" void kernel_launch(void* const* d_in, const int* in_sizes, int n_in,
                              void* d_out, int out_size, void* d_ws, size_t ws_size,
                              hipStream_t stream) {
  (void)in_sizes; (void)n_in; (void)out_size;
  const float* x           = (const float*)d_in[0];
  const float* ssm_proj    = (const float*)d_in[1];
  const float* conv_states = (const float*)d_in[2];
  const float* conv_wts    = (const float*)d_in[3];
  const float* conv_bias   = (const float*)d_in[4];
  float* outp = (float*)d_out;

  const size_t OUT_ELEMS = (size_t)U_DIM * N_DIM;        // 8M floats
  float* ns = outp + OUT_ELEMS;                          // new_states base

  const size_t BT_BYTES = (size_t)N_DIM * K_DIM * sizeof(unsigned short);  // 64MB
  const size_t XB_BYTES = (size_t)U_DIM * K_DIM * sizeof(unsigned short);  // 8MB
  const int GRID = (U_DIM / BM) * (N_DIM / BN);          // 256

  if (ws_size >= BT_BYTES + XB_BYTES) {
    // scratch in d_ws -> GEMM epilogue writes new_states[0..2] directly
    unsigned short* Btbf = (unsigned short*)d_ws;
    unsigned short* xbf  = (unsigned short*)((char*)d_ws + BT_BYTES);
    convert_x_kernel<<<(U_DIM * H_DIM / 4) / 256, 256, 0, stream>>>(x, xbf);
    transpose_b_kernel<<<(N_DIM / 64) * (K_DIM / 64), 256, 0, stream>>>(ssm_proj, Btbf);
    gemm_conv_kernel<true><<<GRID, 512, 0, stream>>>(
        xbf, Btbf, conv_states, conv_wts, conv_bias, outp, ns);
  } else {
    // fallback: scratch inside d_out's new_states[0:2] region, copy after GEMM
    unsigned short* Btbf = (unsigned short*)ns;
    unsigned short* xbf  = (unsigned short*)(ns + 2 * OUT_ELEMS);
    convert_x_kernel<<<(U_DIM * H_DIM / 4) / 256, 256, 0, stream>>>(x, xbf);
    transpose_b_kernel<<<(N_DIM / 64) * (K_DIM / 64), 256, 0, stream>>>(ssm_proj, Btbf);
    gemm_conv_kernel<false><<<GRID, 512, 0, stream>>>(
        xbf, Btbf, conv_states, conv_wts, conv_bias, outp, ns);
    hipMemcpyAsync(ns, conv_states + OUT_ELEMS, 3 * OUT_ELEMS * sizeof(float),
                   hipMemcpyDeviceToDevice, stream);
  }
}